// Round 11
// baseline (75.145 us; speedup 1.0000x reference)
//
#include <hip/hip_runtime.h>
#include <math.h>
#include <float.h>

// Zonotope distance + gradient.
// R11: persistent-ish waves — 1 wave/block, K=4 quads (16 points) per wave.
// A+b for quad k+1 prefetched into LDS via async global_load_lds (zero VGPR
// cost) while quad k computes; counted-vmcnt discipline (wait only at iter
// top, one full iteration after issue). Edges are register loads issued at
// iter start, consumed ~700cy later within the same iteration (no cross-
// phase liveness -> no spill; R9/R10's scratch regressions were exactly
// that). Compute math is R8-verbatim: packed fp32 (per-half IEEE identical),
// v_max3+ballot verdicts, key-packed 4-step butterflies, exact first-index
// tiebreaks. ALL FP op orders match the numpy reference exactly
// (contract(off); no FMA).

typedef float f32x2 __attribute__((ext_vector_type(2)));
typedef float f4u   __attribute__((ext_vector_type(4), aligned(4)));
typedef unsigned long long u64;
typedef unsigned int u32;

constexpr int H = 48;
constexpr int V = 96;
constexpr int K = 4;              // quads per wave
constexpr float ZEPS = 1e-4f;

__device__ __forceinline__ void gload_lds16(const void* g, void* lds) {
  __builtin_amdgcn_global_load_lds(
      (const __attribute__((address_space(1))) void*)g,
      (__attribute__((address_space(3))) void*)lds, 16, 0, 0);
}

__device__ __forceinline__ f32x2 pkmul(f32x2 a, f32x2 b) {
  f32x2 d;
  asm("v_pk_mul_f32 %0, %1, %2" : "=v"(d) : "v"(a), "v"(b));
  return d;
}
__device__ __forceinline__ f32x2 pkadd(f32x2 a, f32x2 b) {
  f32x2 d;
  asm("v_pk_add_f32 %0, %1, %2" : "=v"(d) : "v"(a), "v"(b));
  return d;
}
__device__ __forceinline__ f32x2 pksub(f32x2 a, f32x2 b) {
  f32x2 d;
  asm("v_pk_add_f32 %0, %1, %2 neg_lo:[0,1] neg_hi:[0,1]" : "=v"(d) : "v"(a), "v"(b));
  return d;
}
__device__ __forceinline__ float max3f(float a, float b, float c) {
  float d;
  asm("v_max3_f32 %0, %1, %2, %3" : "=v"(d) : "v"(a), "v"(b), "v"(c));
  return d;
}

struct Edges { f4u a, b, c, d; f32x2 e; };   // 18 floats, named fields only
__device__ __forceinline__ Edges load18(const float* p) {
  Edges r;
  r.a = *(const f4u*)(p);
  r.b = *(const f4u*)(p + 4);
  r.c = *(const f4u*)(p + 8);
  r.d = *(const f4u*)(p + 12);
  r.e = *(const f32x2*)(p + 16);
  return r;
}

struct Pre {
  float fv, fgx, fgy, fgz;
  float nv, ngx, ngy, ngz;
  u32 negbits;
};

__device__ __forceinline__ void edge_upd(
    float px, float py, float pz,
    float x1, float y1, float z1, float x2, float y2, float z2,
    int t, float& bed, int& bte, float& bvx, float& bvy, float& bvz)
{
#pragma clang fp contract(off)
  const float dx = x2 - x1, dy = y2 - y1, dz = z2 - z1;
  const float den = (dx * dx + dy * dy) + dz * dz;
  const float wx = px - x1, wy = py - y1, wz = pz - z1;
  const float th = ((wx * dx + wy * dy) + wz * dz) / den;
  const float ts = th < 0.0f ? 0.0f : (th > 1.0f ? 1.0f : th);
  const float vx = x1 + ts * dx, vy = y1 + ts * dy, vz = z1 + ts * dz;
  const float ex = px - vx, ey = py - vy, ez = pz - vz;
  const float ed = sqrtf((ex * ex + ey * ey) + ez * ez);
  if (ed < bed) { bed = ed; bte = t; bvx = vx; bvy = vy; bvz = vz; }
}

// stage one quad's A+b into LDS (768 floats): A group-major [g*144 + f],
// b at [576 + g*48 + f]. 192 f4 chunks, lane-linear dest (HW: base+lane*16).
__device__ __forceinline__ void stage_quad(
    const float* __restrict__ Ag, const float* __restrict__ bg,
    int n0, int n1, int n2, int n3, float* sbuf, int lane)
{
  #pragma unroll
  for (int r = 0; r < 3; ++r) {
    const int c = 64 * r + lane;
    const int gA = c / 36;             // valid for c<144
    const int wA = c - 36 * gA;
    const int cb = c - 144;
    const int gB = cb / 12;            // valid for c>=144
    const int wB = cb - 12 * gB;
    const bool isA = c < 144;
    const int g = isA ? gA : gB;
    const int n = (g == 0) ? n0 : (g == 1) ? n1 : (g == 2) ? n2 : n3;
    const float* src = isA ? (Ag + (size_t)n * 144 + 4 * wA)
                           : (bg + (size_t)n * 48 + 4 * wB);
    gload_lds16(src, sbuf + 256 * r);  // uniform LDS base; HW adds lane*16
  }
}

// H^2 check + face + neg paths (R8-verbatim math)
__device__ __forceinline__ Pre zono_pre(
    int g, int j,
    float px, float py, float pz,
    float ax0, float ay0, float az0, float ax1, float ay1, float az1,
    float ax2, float ay2, float az2,
    float b0, float b1, float b2,
    float apb0, float apb1, float apb2,
    const float* qxw, const float* qyw, const float* qzw)
{
#pragma clang fp contract(off)
  Pre r;
  const u64 bneg = __ballot(max3f(apb0, apb1, apb2) <= 0.0f);
  u32 negbits = 0;
  if ((bneg & 0x000000000000FFFFull) == 0x000000000000FFFFull) negbits |= 1;
  if ((bneg & 0x00000000FFFF0000ull) == 0x00000000FFFF0000ull) negbits |= 2;
  if ((bneg & 0x0000FFFF00000000ull) == 0x0000FFFF00000000ull) negbits |= 4;
  if ((bneg & 0xFFFF000000000000ull) == 0xFFFF000000000000ull) negbits |= 8;
  r.negbits = negbits;

  const f32x2 AX0 = {ax0, ax0}, AY0 = {ay0, ay0}, AZ0 = {az0, az0}, PB0 = {b0, b0};
  const f32x2 AX1 = {ax1, ax1}, AY1 = {ay1, ay1}, AZ1 = {az1, az1}, PB1 = {b1, b1};
  const f32x2 AX2 = {ax2, ax2}, AY2 = {ay2, ay2}, AZ2 = {az2, az2}, PB2 = {b2, b2};
  u64 bad0 = 0, bad1 = 0, bad2 = 0, bad3 = 0;
  const f32x2* qxp = (const f32x2*)qxw;
  const f32x2* qyp = (const f32x2*)qyw;
  const f32x2* qzp = (const f32x2*)qzw;
  #pragma unroll
  for (int hp = 0; hp < 24; ++hp) {
    const f32x2 QX = qxp[hp], QY = qyp[hp], QZ = qzp[hp];
    f32x2 s0 = pksub(pkadd(pkadd(pkmul(AX0, QX), pkmul(AY0, QY)), pkmul(AZ0, QZ)), PB0);
    f32x2 s1 = pksub(pkadd(pkadd(pkmul(AX1, QX), pkmul(AY1, QY)), pkmul(AZ1, QZ)), PB1);
    f32x2 s2 = pksub(pkadd(pkadd(pkmul(AX2, QX), pkmul(AY2, QY)), pkmul(AZ2, QZ)), PB2);
    const u64 bl0 = __ballot(max3f(s0.x, s1.x, s2.x) <= ZEPS);
    const u64 bl1 = __ballot(max3f(s0.y, s1.y, s2.y) <= ZEPS);
    const u64 c0 = 1ull << (2 * hp), c1 = 1ull << (2 * hp + 1);
    bad0 |= ((~bl0 & 0x000000000000FFFFull) ? c0 : 0) | ((~bl1 & 0x000000000000FFFFull) ? c1 : 0);
    bad1 |= ((~bl0 & 0x00000000FFFF0000ull) ? c0 : 0) | ((~bl1 & 0x00000000FFFF0000ull) ? c1 : 0);
    bad2 |= ((~bl0 & 0x0000FFFF00000000ull) ? c0 : 0) | ((~bl1 & 0x0000FFFF00000000ull) ? c1 : 0);
    bad3 |= ((~bl0 & 0xFFFF000000000000ull) ? c0 : 0) | ((~bl1 & 0xFFFF000000000000ull) ? c1 : 0);
  }
  const u64 MASK48 = (1ull << H) - 1;
  const bool anyface = (((~bad0) | (~bad1) | (~bad2) | (~bad3)) & MASK48) != 0;

  r.fv = INFINITY; r.fgx = 0.f; r.fgy = 0.f; r.fgz = 0.f;
  if (anyface) {
    const u64 badg = (g == 0) ? bad0 : (g == 1) ? bad1 : (g == 2) ? bad2 : bad3;
    const u32 mb = (u32)(badg >> (3 * j));
    const float q0x = qxw[3 * j + 0], q1x = qxw[3 * j + 1], q2x = qxw[3 * j + 2];
    const float q0y = qyw[3 * j + 0], q1y = qyw[3 * j + 1], q2y = qyw[3 * j + 2];
    const float q0z = qzw[3 * j + 0], q1z = qzw[3 * j + 1], q2z = qzw[3 * j + 2];
    float p0 = INFINITY, p1 = INFINITY, p2 = INFINITY;
    if (!(mb & 1)) {
      float dx = px - q0x, dy = py - q0y, dz = pz - q0z;
      p0 = sqrtf((dx * dx + dy * dy) + dz * dz);
    }
    if (!(mb & 2)) {
      float dx = px - q1x, dy = py - q1y, dz = pz - q1z;
      p1 = sqrtf((dx * dx + dy * dy) + dz * dz);
    }
    if (!(mb & 4)) {
      float dx = px - q2x, dy = py - q2y, dz = pz - q2z;
      p2 = sqrtf((dx * dx + dy * dy) + dz * dz);
    }
    float bv = p0; int bk = 0;
    if (p1 < bv) { bv = p1; bk = 1; }
    if (p2 < bv) { bv = p2; bk = 2; }
    u64 key = ((u64)__float_as_uint(bv) << 16) | (u32)(3 * j + bk);
    #pragma unroll
    for (int off = 8; off; off >>= 1) {
      u64 o = __shfl_xor(key, off);
      if (o < key) key = o;
    }
    r.fv = __uint_as_float((u32)(key >> 16));
    const int ks = (int)(key & 0xFFFF);
    const int owner = 16 * g + ks / 3;
    const int ms = ks - 3 * (ks / 3);
    const float sx0 = __shfl(ax0, owner), sx1 = __shfl(ax1, owner), sx2 = __shfl(ax2, owner);
    const float sy0 = __shfl(ay0, owner), sy1 = __shfl(ay1, owner), sy2 = __shfl(ay2, owner);
    const float sz0 = __shfl(az0, owner), sz1 = __shfl(az1, owner), sz2 = __shfl(az2, owner);
    r.fgx = (ms == 0) ? sx0 : (ms == 1) ? sx1 : sx2;
    r.fgy = (ms == 0) ? sy0 : (ms == 1) ? sy1 : sy2;
    r.fgz = (ms == 0) ? sz0 : (ms == 1) ? sz1 : sz2;
  }

  r.nv = 0.f; r.ngx = 0.f; r.ngy = 0.f; r.ngz = 0.f;
  if (negbits) {
    float bv = apb0; int bk = 0;
    if (apb1 > bv) { bv = apb1; bk = 1; }
    if (apb2 > bv) { bv = apb2; bk = 2; }
    u32 bits = __float_as_uint(bv);
    u32 obits = (bits >> 31) ? ~bits : (bits | 0x80000000u);
    u64 key = ((u64)obits << 16) | (u32)(0xFFFF - (3 * j + bk));
    #pragma unroll
    for (int off = 8; off; off >>= 1) {
      u64 o = __shfl_xor(key, off);
      if (o > key) key = o;
    }
    const int ks = (int)(0xFFFF - (key & 0xFFFF));
    const int owner = 16 * g + ks / 3;
    const int ms = ks - 3 * (ks / 3);
    const float v0 = __shfl(apb0, owner), v1 = __shfl(apb1, owner), v2 = __shfl(apb2, owner);
    r.nv = (ms == 0) ? v0 : (ms == 1) ? v1 : v2;
    const float sx0 = __shfl(ax0, owner), sx1 = __shfl(ax1, owner), sx2 = __shfl(ax2, owner);
    const float sy0 = __shfl(ay0, owner), sy1 = __shfl(ay1, owner), sy2 = __shfl(ay2, owner);
    const float sz0 = __shfl(az0, owner), sz1 = __shfl(az1, owner), sz2 = __shfl(az2, owner);
    r.ngx = (ms == 0) ? sx0 : (ms == 1) ? sx1 : sx2;
    r.ngy = (ms == 0) ? sy0 : (ms == 1) ? sy1 : sy2;
    r.ngz = (ms == 0) ? sz0 : (ms == 1) ? sz1 : sz2;
  }
  return r;
}

__device__ __forceinline__ void edges6(
    float px, float py, float pz, const Edges& E, const Edges& F,
    float& bed, int& bte, float& bvx, float& bvy, float& bvz)
{
  bed = INFINITY; bte = 0; bvx = 0.f; bvy = 0.f; bvz = 0.f;
  edge_upd(px, py, pz, E.a.x, E.a.y, E.a.z, F.a.x, F.a.y, F.a.z, 0, bed, bte, bvx, bvy, bvz);
  edge_upd(px, py, pz, E.a.w, E.b.x, E.b.y, F.a.w, F.b.x, F.b.y, 1, bed, bte, bvx, bvy, bvz);
  edge_upd(px, py, pz, E.b.z, E.b.w, E.c.x, F.b.z, F.b.w, F.c.x, 2, bed, bte, bvx, bvy, bvz);
  edge_upd(px, py, pz, E.c.y, E.c.z, E.c.w, F.c.y, F.c.z, F.c.w, 3, bed, bte, bvx, bvy, bvz);
  edge_upd(px, py, pz, E.d.x, E.d.y, E.d.z, F.d.x, F.d.y, F.d.z, 4, bed, bte, bvx, bvy, bvz);
  edge_upd(px, py, pz, E.d.w, E.e.x, E.e.y, F.d.w, F.e.x, F.e.y, 5, bed, bte, bvx, bvy, bvz);
}

__device__ __forceinline__ void finish_point(
    int n, int g, int j, int N,
    float px, float py, float pz, const Pre& P,
    float bed, int bte, float bvx, float bvy, float bvz,
    float* __restrict__ out)
{
#pragma clang fp contract(off)
  u64 ekey = ((u64)__float_as_uint(bed) << 16) | (u32)(6 * j + bte);
  #pragma unroll
  for (int off = 8; off; off >>= 1) {
    u64 o = __shfl_xor(ekey, off);
    if (o < ekey) ekey = o;
  }
  const float m = __uint_as_float((u32)(ekey >> 16));
  const int el = (int)(ekey & 0xFFFF);
  const int wl = 16 * g + el / 6;
  const float wvx = __shfl(bvx, wl);
  const float wvy = __shfl(bvy, wl);
  const float wvz = __shfl(bvz, wl);

  const bool isneg = (P.negbits >> g) & 1;
  const bool use_edge = (m < P.fv);
  const float pd = (j == 0) ? px : (j == 1) ? py : pz;
  const float wd = (j == 0) ? wvx : (j == 1) ? wvy : wvz;
  const float fd = (j == 0) ? P.fgx : (j == 1) ? P.fgy : P.fgz;
  const float nd = (j == 0) ? P.ngx : (j == 1) ? P.ngy : P.ngz;
  float dist, gnum, gden = 1.0f;
  if (isneg) {
    dist = P.nv; gnum = nd;
  } else if (use_edge) {
    dist = m; gnum = pd - wd; gden = m;
  } else {
    dist = P.fv; gnum = fd;
  }
  const float gr = gnum / gden;
  if (j < 3) out[(size_t)N + 3 * (size_t)n + j] = gr;
  if (j == 3) out[n] = dist;
}

__global__ __launch_bounds__(64, 4) void zono_dist_kernel(
    const float* __restrict__ point,   // [N,3]
    const float* __restrict__ Ag,      // [N,H,3]
    const float* __restrict__ bg,      // [N,H]
    const float* __restrict__ v1g,     // [N,V,3]
    const float* __restrict__ v2g,     // [N,V,3]
    float* __restrict__ out,           // [N] dist ++ [N,3] grad
    int N)
{
#pragma clang fp contract(off)
  __shared__ __align__(16) float sAB[2][768];     // A+b double buffer
  __shared__ __align__(16) float sQ[3][4][56];    // q broadcast (per iter)

  const int lane = threadIdx.x & 63;
  const int g = lane >> 4;
  const int j = lane & 15;
  const int qbase = blockIdx.x * K;               // first quad for this wave

  // prologue: stage quad 0's A+b
  {
    const int q0 = qbase;
    int n0 = q0 * 4 + 0, n1 = q0 * 4 + 1, n2 = q0 * 4 + 2, n3 = q0 * 4 + 3;
    if (n0 >= N) n0 = N - 1;
    if (n1 >= N) n1 = N - 1;
    if (n2 >= N) n2 = N - 1;
    if (n3 >= N) n3 = N - 1;
    stage_quad(Ag, bg, n0, n1, n2, n3, &sAB[0][0], lane);
  }

  float* qxw = &sQ[0][g][0];
  float* qyw = &sQ[1][g][0];
  float* qzw = &sQ[2][g][0];

  #pragma unroll 1
  for (int k = 0; k < K; ++k) {
    // A+b(k) staged one iteration ago -> steady-state zero stall
    asm volatile("s_waitcnt vmcnt(0)" ::: "memory");
    __builtin_amdgcn_sched_barrier(0);

    const int quad = qbase + k;
    int n = quad * 4 + g;
    if (n >= N) n = N - 1;

    // point (uniform per group via first lane of group is overkill; direct)
    const float px = point[3 * (size_t)n + 0];
    const float py = point[3 * (size_t)n + 1];
    const float pz = point[3 * (size_t)n + 2];

    // edges for THIS quad: issued now, consumed after H^2 (~700cy hidden)
    const Edges E = load18(v1g + (size_t)n * (V * 3) + 18 * j);
    const Edges F = load18(v2g + (size_t)n * (V * 3) + 18 * j);

    // prefetch next quad's A+b
    if (k + 1 < K) {
      const int q1 = quad + 1;
      int m0 = q1 * 4 + 0, m1 = q1 * 4 + 1, m2 = q1 * 4 + 2, m3 = q1 * 4 + 3;
      if (m0 >= N) m0 = N - 1;
      if (m1 >= N) m1 = N - 1;
      if (m2 >= N) m2 = N - 1;
      if (m3 >= N) m3 = N - 1;
      stage_quad(Ag, bg, m0, m1, m2, m3, &sAB[(k + 1) & 1][0], lane);
    }

    // A+b of current quad from LDS
    const float* cur = &sAB[k & 1][0];
    const float* sA = cur + g * 144 + 9 * j;
    const float ax0 = sA[0], ay0 = sA[1], az0 = sA[2];
    const float ax1 = sA[3], ay1 = sA[4], az1 = sA[5];
    const float ax2 = sA[6], ay2 = sA[7], az2 = sA[8];
    const float* sB = cur + 576 + g * 48 + 3 * j;
    const float b0 = sB[0], b1 = sB[1], b2 = sB[2];

    // signed facet offsets + projections (exact ref op order)
    const float apb0 = ((ax0 * px + ay0 * py) + az0 * pz) - b0;
    const float apb1 = ((ax1 * px + ay1 * py) + az1 * pz) - b1;
    const float apb2 = ((ax2 * px + ay2 * py) + az2 * pz) - b2;
    qxw[3 * j + 0] = px - apb0 * ax0;
    qxw[3 * j + 1] = px - apb1 * ax1;
    qxw[3 * j + 2] = px - apb2 * ax2;
    qyw[3 * j + 0] = py - apb0 * ay0;
    qyw[3 * j + 1] = py - apb1 * ay1;
    qyw[3 * j + 2] = py - apb2 * ay2;
    qzw[3 * j + 0] = pz - apb0 * az0;
    qzw[3 * j + 1] = pz - apb1 * az1;
    qzw[3 * j + 2] = pz - apb2 * az2;

    const Pre P = zono_pre(g, j, px, py, pz,
                           ax0, ay0, az0, ax1, ay1, az1, ax2, ay2, az2,
                           b0, b1, b2, apb0, apb1, apb2,
                           qxw, qyw, qzw);
    float bed, bvx, bvy, bvz; int bte;
    edges6(px, py, pz, E, F, bed, bte, bvx, bvy, bvz);
    finish_point(n, g, j, N, px, py, pz, P, bed, bte, bvx, bvy, bvz, out);
  }
}

extern "C" void kernel_launch(void* const* d_in, const int* in_sizes, int n_in,
                              void* d_out, int out_size, void* d_ws, size_t ws_size,
                              hipStream_t stream) {
  const float* point = (const float*)d_in[0];
  const float* Ag    = (const float*)d_in[1];
  const float* bg    = (const float*)d_in[2];
  const float* v1g   = (const float*)d_in[3];
  const float* v2g   = (const float*)d_in[4];
  float* out = (float*)d_out;

  const int N = in_sizes[0] / 3;
  const int ppb = 4 * K;                    // 16 points per block (1 wave)
  const int blocks = (N + ppb - 1) / ppb;
  zono_dist_kernel<<<blocks, 64, 0, stream>>>(point, Ag, bg, v1g, v2g, out, N);
}

// Round 12
// 45.545 us; speedup vs baseline: 1.6499x; 1.6499x over previous
//
#include <hip/hip_runtime.h>
#include <math.h>
#include <float.h>

// Zonotope distance + gradient.
// R12 = R8 (proven 46.5us, clean codegen) + two LOCAL rewrites:
//   (1) H^2 loop reads q via ds_read_b128 (12 iters x 3 reads, 2 h-pairs
//       per iter) instead of 24 x 3 b64 — halves DS ops; in-register split.
//   (2) edge math packed f32x2, 3 pairs per lane (R7-proven asm ops);
//       divs/sqrts stay scalar IEEE; strict-< keeps exact first-index argmin.
// Structure, reductions, writes = R8 verbatim. ALL FP op orders match the
// numpy reference exactly (contract(off); no FMA; packed ops per-half IEEE
// identical).

typedef float f32x2 __attribute__((ext_vector_type(2)));
typedef float f32x4 __attribute__((ext_vector_type(4)));
typedef float f4u   __attribute__((ext_vector_type(4), aligned(4)));
typedef unsigned long long u64;
typedef unsigned int u32;

constexpr int H = 48;
constexpr int V = 96;
constexpr int WPB = 4;            // waves per block
constexpr int PPW = 4;            // points per wave
constexpr float ZEPS = 1e-4f;

__device__ __forceinline__ f32x2 pkmul(f32x2 a, f32x2 b) {
  f32x2 d;
  asm("v_pk_mul_f32 %0, %1, %2" : "=v"(d) : "v"(a), "v"(b));
  return d;
}
__device__ __forceinline__ f32x2 pkadd(f32x2 a, f32x2 b) {
  f32x2 d;
  asm("v_pk_add_f32 %0, %1, %2" : "=v"(d) : "v"(a), "v"(b));
  return d;
}
// a - b per half (add of negated src1; IEEE-exact)
__device__ __forceinline__ f32x2 pksub(f32x2 a, f32x2 b) {
  f32x2 d;
  asm("v_pk_add_f32 %0, %1, %2 neg_lo:[0,1] neg_hi:[0,1]" : "=v"(d) : "v"(a), "v"(b));
  return d;
}
__device__ __forceinline__ float max3f(float a, float b, float c) {
  float d;
  asm("v_max3_f32 %0, %1, %2, %3" : "=v"(d) : "v"(a), "v"(b), "v"(c));
  return d;
}

__global__ __launch_bounds__(256, 4) void zono_dist_kernel(
    const float* __restrict__ point,   // [N,3]
    const float* __restrict__ Ag,      // [N,H,3]
    const float* __restrict__ bg,      // [N,H]
    const float* __restrict__ v1g,     // [N,V,3]
    const float* __restrict__ v2g,     // [N,V,3]
    float* __restrict__ out,           // [N] dist ++ [N,3] grad
    int N)
{
#pragma clang fp contract(off)
  // q storage: [wave][comp][group][56]; group bases are banks {0,24,16,8},
  // 4-bank spans per b128 read -> disjoint across groups, conflict-free.
  __shared__ __align__(16) float sQ[WPB][3][PPW][56];

  const int wave = threadIdx.x >> 6;
  const int lane = threadIdx.x & 63;
  const int g = lane >> 4;          // group (point within wave)
  const int j = lane & 15;          // lane within group
  int n = blockIdx.x * (WPB * PPW) + wave * PPW + g;
  if (n >= N) n = N - 1;            // duplicate work, duplicate-same writes

  // ---- loads ----
  const float px = point[3 * (size_t)n + 0];
  const float py = point[3 * (size_t)n + 1];
  const float pz = point[3 * (size_t)n + 2];

  const float* ap = Ag + (size_t)n * (H * 3) + 9 * j;   // planes 3j..3j+2
  f4u A0 = *(const f4u*)(ap);        // a0x a0y a0z a1x
  f4u A1 = *(const f4u*)(ap + 4);    // a1y a1z a2x a2y
  const float a2z = ap[8];
  const float* bp = bg + (size_t)n * H + 3 * j;
  const float b0 = bp[0], b1 = bp[1], b2 = bp[2];

  // edges 6j..6j+5: 18 floats per endpoint array, issued early
  const float* e1p = v1g + (size_t)n * (V * 3) + 18 * j;
  const float* e2p = v2g + (size_t)n * (V * 3) + 18 * j;
  f4u Ea = *(const f4u*)(e1p);      f4u Eb = *(const f4u*)(e1p + 4);
  f4u Ec = *(const f4u*)(e1p + 8);  f4u Ed = *(const f4u*)(e1p + 12);
  f32x2 Ee = *(const f32x2*)(e1p + 16);
  f4u Fa = *(const f4u*)(e2p);      f4u Fb = *(const f4u*)(e2p + 4);
  f4u Fc = *(const f4u*)(e2p + 8);  f4u Fd = *(const f4u*)(e2p + 12);
  f32x2 Fe = *(const f32x2*)(e2p + 16);

  const float ax0 = A0.x, ay0 = A0.y, az0 = A0.z;
  const float ax1 = A0.w, ay1 = A1.x, az1 = A1.y;
  const float ax2 = A1.z, ay2 = A1.w, az2 = a2z;

  // ---- signed facet offsets + projections (exact ref op order) ----
  const float apb0 = ((ax0 * px + ay0 * py) + az0 * pz) - b0;
  const float apb1 = ((ax1 * px + ay1 * py) + az1 * pz) - b1;
  const float apb2 = ((ax2 * px + ay2 * py) + az2 * pz) - b2;
  const float q0x = px - apb0 * ax0, q0y = py - apb0 * ay0, q0z = pz - apb0 * az0;
  const float q1x = px - apb1 * ax1, q1y = py - apb1 * ay1, q1z = pz - apb1 * az1;
  const float q2x = px - apb2 * ax2, q2y = py - apb2 * ay2, q2z = pz - apb2 * az2;

  float* qxw = &sQ[wave][0][g][0];
  float* qyw = &sQ[wave][1][g][0];
  float* qzw = &sQ[wave][2][g][0];
  qxw[3 * j + 0] = q0x; qxw[3 * j + 1] = q1x; qxw[3 * j + 2] = q2x;
  qyw[3 * j + 0] = q0y; qyw[3 * j + 1] = q1y; qyw[3 * j + 2] = q2y;
  qzw[3 * j + 0] = q0z; qzw[3 * j + 1] = q1z; qzw[3 * j + 2] = q2z;

  // ---- is_neg per group ----
  const u64 bneg = __ballot(max3f(apb0, apb1, apb2) <= 0.0f);
  u32 negbits = 0;
  if ((bneg & 0x000000000000FFFFull) == 0x000000000000FFFFull) negbits |= 1;
  if ((bneg & 0x00000000FFFF0000ull) == 0x00000000FFFF0000ull) negbits |= 2;
  if ((bneg & 0x0000FFFF00000000ull) == 0x0000FFFF00000000ull) negbits |= 4;
  if ((bneg & 0xFFFF000000000000ull) == 0xFFFF000000000000ull) negbits |= 8;

  // ---- prebuilt broadcast pairs (loop-invariant) ----
  const f32x2 AX0 = {ax0, ax0}, AY0 = {ay0, ay0}, AZ0 = {az0, az0}, PB0 = {b0, b0};
  const f32x2 AX1 = {ax1, ax1}, AY1 = {ay1, ay1}, AZ1 = {az1, az1}, PB1 = {b1, b1};
  const f32x2 AX2 = {ax2, ax2}, AY2 = {ay2, ay2}, AZ2 = {az2, az2}, PB2 = {b2, b2};

  // ---- H^2 check: 12 iterations, 2 h-pairs (4 candidates) each ----
  u64 bad0 = 0, bad1 = 0, bad2 = 0, bad3 = 0;   // uniform, per group
  const f32x4* qx4 = (const f32x4*)qxw;
  const f32x4* qy4 = (const f32x4*)qyw;
  const f32x4* qz4 = (const f32x4*)qzw;
  #pragma unroll
  for (int it = 0; it < 12; ++it) {
    const f32x4 X = qx4[it], Y = qy4[it], Z = qz4[it];   // b128 broadcasts
    const f32x2 xlo = __builtin_shufflevector(X, X, 0, 1);
    const f32x2 xhi = __builtin_shufflevector(X, X, 2, 3);
    const f32x2 ylo = __builtin_shufflevector(Y, Y, 0, 1);
    const f32x2 yhi = __builtin_shufflevector(Y, Y, 2, 3);
    const f32x2 zlo = __builtin_shufflevector(Z, Z, 0, 1);
    const f32x2 zhi = __builtin_shufflevector(Z, Z, 2, 3);
    // lo pair: candidates h = 4it, 4it+1
    f32x2 s0 = pksub(pkadd(pkadd(pkmul(AX0, xlo), pkmul(AY0, ylo)), pkmul(AZ0, zlo)), PB0);
    f32x2 s1 = pksub(pkadd(pkadd(pkmul(AX1, xlo), pkmul(AY1, ylo)), pkmul(AZ1, zlo)), PB1);
    f32x2 s2 = pksub(pkadd(pkadd(pkmul(AX2, xlo), pkmul(AY2, ylo)), pkmul(AZ2, zlo)), PB2);
    // hi pair: candidates h = 4it+2, 4it+3
    f32x2 t0 = pksub(pkadd(pkadd(pkmul(AX0, xhi), pkmul(AY0, yhi)), pkmul(AZ0, zhi)), PB0);
    f32x2 t1 = pksub(pkadd(pkadd(pkmul(AX1, xhi), pkmul(AY1, yhi)), pkmul(AZ1, zhi)), PB1);
    f32x2 t2 = pksub(pkadd(pkadd(pkmul(AX2, xhi), pkmul(AY2, yhi)), pkmul(AZ2, zhi)), PB2);
    const u64 bl0 = __ballot(max3f(s0.x, s1.x, s2.x) <= ZEPS);
    const u64 bl1 = __ballot(max3f(s0.y, s1.y, s2.y) <= ZEPS);
    const u64 bl2 = __ballot(max3f(t0.x, t1.x, t2.x) <= ZEPS);
    const u64 bl3 = __ballot(max3f(t0.y, t1.y, t2.y) <= ZEPS);
    const int h = 4 * it;
    const u64 c0 = 1ull << h, c1 = 2ull << h, c2 = 4ull << h, c3 = 8ull << h;
    bad0 |= ((~bl0 & 0x000000000000FFFFull) ? c0 : 0) | ((~bl1 & 0x000000000000FFFFull) ? c1 : 0)
          | ((~bl2 & 0x000000000000FFFFull) ? c2 : 0) | ((~bl3 & 0x000000000000FFFFull) ? c3 : 0);
    bad1 |= ((~bl0 & 0x00000000FFFF0000ull) ? c0 : 0) | ((~bl1 & 0x00000000FFFF0000ull) ? c1 : 0)
          | ((~bl2 & 0x00000000FFFF0000ull) ? c2 : 0) | ((~bl3 & 0x00000000FFFF0000ull) ? c3 : 0);
    bad2 |= ((~bl0 & 0x0000FFFF00000000ull) ? c0 : 0) | ((~bl1 & 0x0000FFFF00000000ull) ? c1 : 0)
          | ((~bl2 & 0x0000FFFF00000000ull) ? c2 : 0) | ((~bl3 & 0x0000FFFF00000000ull) ? c3 : 0);
    bad3 |= ((~bl0 & 0xFFFF000000000000ull) ? c0 : 0) | ((~bl1 & 0xFFFF000000000000ull) ? c1 : 0)
          | ((~bl2 & 0xFFFF000000000000ull) ? c2 : 0) | ((~bl3 & 0xFFFF000000000000ull) ? c3 : 0);
  }
  const u64 MASK48 = (1ull << H) - 1;
  const bool anyface = (((~bad0) | (~bad1) | (~bad2) | (~bad3)) & MASK48) != 0;

  // ---- face path (gated; rare) ----
  float fv = INFINITY, fgx = 0.f, fgy = 0.f, fgz = 0.f;
  if (anyface) {
    const u64 badg = (g == 0) ? bad0 : (g == 1) ? bad1 : (g == 2) ? bad2 : bad3;
    const u32 mb = (u32)(badg >> (3 * j));
    float p0 = INFINITY, p1 = INFINITY, p2 = INFINITY;
    if (!(mb & 1)) {
      float dx = px - q0x, dy = py - q0y, dz = pz - q0z;
      p0 = sqrtf((dx * dx + dy * dy) + dz * dz);
    }
    if (!(mb & 2)) {
      float dx = px - q1x, dy = py - q1y, dz = pz - q1z;
      p1 = sqrtf((dx * dx + dy * dy) + dz * dz);
    }
    if (!(mb & 4)) {
      float dx = px - q2x, dy = py - q2y, dz = pz - q2z;
      p2 = sqrtf((dx * dx + dy * dy) + dz * dz);
    }
    float bv = p0; int bk = 0;
    if (p1 < bv) { bv = p1; bk = 1; }
    if (p2 < bv) { bv = p2; bk = 2; }
    u64 key = ((u64)__float_as_uint(bv) << 16) | (u32)(3 * j + bk);
    #pragma unroll
    for (int off = 8; off; off >>= 1) {
      u64 o = __shfl_xor(key, off);
      if (o < key) key = o;
    }
    fv = __uint_as_float((u32)(key >> 16));
    const int ks = (int)(key & 0xFFFF);
    const int owner = 16 * g + ks / 3;
    const int ms = ks - 3 * (ks / 3);
    const float sx0 = __shfl(ax0, owner), sx1 = __shfl(ax1, owner), sx2 = __shfl(ax2, owner);
    const float sy0 = __shfl(ay0, owner), sy1 = __shfl(ay1, owner), sy2 = __shfl(ay2, owner);
    const float sz0 = __shfl(az0, owner), sz1 = __shfl(az1, owner), sz2 = __shfl(az2, owner);
    fgx = (ms == 0) ? sx0 : (ms == 1) ? sx1 : sx2;
    fgy = (ms == 0) ? sy0 : (ms == 1) ? sy1 : sy2;
    fgz = (ms == 0) ? sz0 : (ms == 1) ? sz1 : sz2;
  }

  // ---- inside-zonotope path (gated; rare) ----
  float nv = 0.f, ngx = 0.f, ngy = 0.f, ngz = 0.f;
  if (negbits) {
    float bv = apb0; int bk = 0;                  // strict > keeps first k
    if (apb1 > bv) { bv = apb1; bk = 1; }
    if (apb2 > bv) { bv = apb2; bk = 2; }
    u32 bits = __float_as_uint(bv);
    u32 obits = (bits >> 31) ? ~bits : (bits | 0x80000000u);   // monotone
    u64 key = ((u64)obits << 16) | (u32)(0xFFFF - (3 * j + bk));
    #pragma unroll
    for (int off = 8; off; off >>= 1) {
      u64 o = __shfl_xor(key, off);
      if (o > key) key = o;
    }
    const int ks = (int)(0xFFFF - (key & 0xFFFF));
    const int owner = 16 * g + ks / 3;
    const int ms = ks - 3 * (ks / 3);
    const float v0 = __shfl(apb0, owner), v1 = __shfl(apb1, owner), v2 = __shfl(apb2, owner);
    nv = (ms == 0) ? v0 : (ms == 1) ? v1 : v2;
    const float sx0 = __shfl(ax0, owner), sx1 = __shfl(ax1, owner), sx2 = __shfl(ax2, owner);
    const float sy0 = __shfl(ay0, owner), sy1 = __shfl(ay1, owner), sy2 = __shfl(ay2, owner);
    const float sz0 = __shfl(az0, owner), sz1 = __shfl(az1, owner), sz2 = __shfl(az2, owner);
    ngx = (ms == 0) ? sx0 : (ms == 1) ? sx1 : sx2;
    ngy = (ms == 0) ? sy0 : (ms == 1) ? sy1 : sy2;
    ngz = (ms == 0) ? sz0 : (ms == 1) ? sz1 : sz2;
  }

  // ---- edge distances: 3 packed pairs (edges 2t,2t+1), exact ref math ----
  float bed = INFINITY, bvx = 0.f, bvy = 0.f, bvz = 0.f;
  int bte = 0;
  {
    const f32x2 Px = {px, px}, Py = {py, py}, Pz = {pz, pz};
    #pragma unroll
    for (int t = 0; t < 3; ++t) {
      f32x2 X1, Y1, Z1, X2, Y2, Z2;
      if (t == 0) {
        X1 = f32x2{Ea.x, Ea.w}; Y1 = f32x2{Ea.y, Eb.x}; Z1 = f32x2{Ea.z, Eb.y};
        X2 = f32x2{Fa.x, Fa.w}; Y2 = f32x2{Fa.y, Fb.x}; Z2 = f32x2{Fa.z, Fb.y};
      } else if (t == 1) {
        X1 = f32x2{Eb.z, Ec.y}; Y1 = f32x2{Eb.w, Ec.z}; Z1 = f32x2{Ec.x, Ec.w};
        X2 = f32x2{Fb.z, Fc.y}; Y2 = f32x2{Fb.w, Fc.z}; Z2 = f32x2{Fc.x, Fc.w};
      } else {
        X1 = f32x2{Ed.x, Ed.w}; Y1 = f32x2{Ed.y, Ee.x}; Z1 = f32x2{Ed.z, Ee.y};
        X2 = f32x2{Fd.x, Fd.w}; Y2 = f32x2{Fd.y, Fe.x}; Z2 = f32x2{Fd.z, Fe.y};
      }
      const f32x2 dx = pksub(X2, X1), dy = pksub(Y2, Y1), dz = pksub(Z2, Z1);
      const f32x2 den = pkadd(pkadd(pkmul(dx, dx), pkmul(dy, dy)), pkmul(dz, dz));
      const f32x2 wx = pksub(Px, X1), wy = pksub(Py, Y1), wz = pksub(Pz, Z1);
      const f32x2 num = pkadd(pkadd(pkmul(wx, dx), pkmul(wy, dy)), pkmul(wz, dz));
      const float th0 = num.x / den.x;             // exact IEEE divs (ref)
      const float th1 = num.y / den.y;
      const float t0 = th0 < 0.0f ? 0.0f : (th0 > 1.0f ? 1.0f : th0);
      const float t1 = th1 < 0.0f ? 0.0f : (th1 > 1.0f ? 1.0f : th1);
      const f32x2 tv = {t0, t1};
      const f32x2 Vx = pkadd(X1, pkmul(tv, dx));   // ref: v1 + t*d
      const f32x2 Vy = pkadd(Y1, pkmul(tv, dy));
      const f32x2 Vz = pkadd(Z1, pkmul(tv, dz));
      const f32x2 Ex = pksub(Px, Vx), Ey = pksub(Py, Vy), Ez = pksub(Pz, Vz);
      const f32x2 ss = pkadd(pkadd(pkmul(Ex, Ex), pkmul(Ey, Ey)), pkmul(Ez, Ez));
      const float ed0 = sqrtf(ss.x);
      const float ed1 = sqrtf(ss.y);
      const bool pick = ed1 < ed0;                 // tie -> lower index
      const float edp = pick ? ed1 : ed0;
      if (edp < bed) {                             // strict -> first index
        bed = edp;
        bte = 2 * t + (pick ? 1 : 0);
        bvx = pick ? Vx.y : Vx.x;
        bvy = pick ? Vy.y : Vy.x;
        bvz = pick ? Vz.y : Vz.x;
      }
    }
  }
  u64 ekey = ((u64)__float_as_uint(bed) << 16) | (u32)(6 * j + bte);
  #pragma unroll
  for (int off = 8; off; off >>= 1) {
    u64 o = __shfl_xor(ekey, off);
    if (o < ekey) ekey = o;
  }
  const float m = __uint_as_float((u32)(ekey >> 16));
  const int el = (int)(ekey & 0xFFFF);
  const int wl = 16 * g + el / 6;
  const float wvx = __shfl(bvx, wl);
  const float wvy = __shfl(bvy, wl);
  const float wvz = __shfl(bvz, wl);

  // ---- combine; lanes j=0..2 write grad comps, j=3 writes dist ----
  const bool isneg = (negbits >> g) & 1;
  const bool use_edge = (m < fv);
  const float pd = (j == 0) ? px : (j == 1) ? py : pz;
  const float wd = (j == 0) ? wvx : (j == 1) ? wvy : wvz;
  const float fd = (j == 0) ? fgx : (j == 1) ? fgy : fgz;
  const float nd = (j == 0) ? ngx : (j == 1) ? ngy : ngz;
  float dist, gnum, gden = 1.0f;
  if (isneg) {
    dist = nv; gnum = nd;
  } else if (use_edge) {
    dist = m; gnum = pd - wd; gden = m;
  } else {
    dist = fv; gnum = fd;
  }
  const float gr = gnum / gden;
  if (j < 3) out[(size_t)N + 3 * (size_t)n + j] = gr;
  if (j == 3) out[n] = dist;
}

extern "C" void kernel_launch(void* const* d_in, const int* in_sizes, int n_in,
                              void* d_out, int out_size, void* d_ws, size_t ws_size,
                              hipStream_t stream) {
  const float* point = (const float*)d_in[0];
  const float* Ag    = (const float*)d_in[1];
  const float* bg    = (const float*)d_in[2];
  const float* v1g   = (const float*)d_in[3];
  const float* v2g   = (const float*)d_in[4];
  float* out = (float*)d_out;

  const int N = in_sizes[0] / 3;
  const int ppb = WPB * PPW;   // 16 points per block
  const int blocks = (N + ppb - 1) / ppb;
  zono_dist_kernel<<<blocks, WPB * 64, 0, stream>>>(point, Ag, bg, v1g, v2g, out, N);
}

// Round 13
// 45.240 us; speedup vs baseline: 1.6610x; 1.0067x over previous
//
#include <hip/hip_runtime.h>
#include <math.h>
#include <float.h>

// Zonotope distance + gradient.
// R13 = R12 + lightweight edge reduction:
//   f32 value-min butterfly (4 serial steps) + ballot/ctz first-winner
//   + 3 parallel payload shfls, replacing the u64-key butterfly
//   (8 serial bpermutes + u64 chains). Exact first-index argmin semantics
//   (lane order == index order; strict-< within lane).
// Everything else R12-verbatim. ALL FP op orders match the numpy reference
// exactly (contract(off); no FMA; packed ops per-half IEEE identical).

typedef float f32x2 __attribute__((ext_vector_type(2)));
typedef float f32x4 __attribute__((ext_vector_type(4)));
typedef float f4u   __attribute__((ext_vector_type(4), aligned(4)));
typedef unsigned long long u64;
typedef unsigned int u32;

constexpr int H = 48;
constexpr int V = 96;
constexpr int WPB = 4;            // waves per block
constexpr int PPW = 4;            // points per wave
constexpr float ZEPS = 1e-4f;

__device__ __forceinline__ f32x2 pkmul(f32x2 a, f32x2 b) {
  f32x2 d;
  asm("v_pk_mul_f32 %0, %1, %2" : "=v"(d) : "v"(a), "v"(b));
  return d;
}
__device__ __forceinline__ f32x2 pkadd(f32x2 a, f32x2 b) {
  f32x2 d;
  asm("v_pk_add_f32 %0, %1, %2" : "=v"(d) : "v"(a), "v"(b));
  return d;
}
// a - b per half (add of negated src1; IEEE-exact)
__device__ __forceinline__ f32x2 pksub(f32x2 a, f32x2 b) {
  f32x2 d;
  asm("v_pk_add_f32 %0, %1, %2 neg_lo:[0,1] neg_hi:[0,1]" : "=v"(d) : "v"(a), "v"(b));
  return d;
}
__device__ __forceinline__ float max3f(float a, float b, float c) {
  float d;
  asm("v_max3_f32 %0, %1, %2, %3" : "=v"(d) : "v"(a), "v"(b), "v"(c));
  return d;
}

__global__ __launch_bounds__(256, 4) void zono_dist_kernel(
    const float* __restrict__ point,   // [N,3]
    const float* __restrict__ Ag,      // [N,H,3]
    const float* __restrict__ bg,      // [N,H]
    const float* __restrict__ v1g,     // [N,V,3]
    const float* __restrict__ v2g,     // [N,V,3]
    float* __restrict__ out,           // [N] dist ++ [N,3] grad
    int N)
{
#pragma clang fp contract(off)
  // q storage: [wave][comp][group][56]; group bases are banks {0,24,16,8},
  // 4-bank spans per b128 read -> disjoint across groups, conflict-free.
  __shared__ __align__(16) float sQ[WPB][3][PPW][56];

  const int wave = threadIdx.x >> 6;
  const int lane = threadIdx.x & 63;
  const int g = lane >> 4;          // group (point within wave)
  const int j = lane & 15;          // lane within group
  int n = blockIdx.x * (WPB * PPW) + wave * PPW + g;
  if (n >= N) n = N - 1;            // duplicate work, duplicate-same writes

  // ---- loads ----
  const float px = point[3 * (size_t)n + 0];
  const float py = point[3 * (size_t)n + 1];
  const float pz = point[3 * (size_t)n + 2];

  const float* ap = Ag + (size_t)n * (H * 3) + 9 * j;   // planes 3j..3j+2
  f4u A0 = *(const f4u*)(ap);        // a0x a0y a0z a1x
  f4u A1 = *(const f4u*)(ap + 4);    // a1y a1z a2x a2y
  const float a2z = ap[8];
  const float* bp = bg + (size_t)n * H + 3 * j;
  const float b0 = bp[0], b1 = bp[1], b2 = bp[2];

  // edges 6j..6j+5: 18 floats per endpoint array, issued early
  const float* e1p = v1g + (size_t)n * (V * 3) + 18 * j;
  const float* e2p = v2g + (size_t)n * (V * 3) + 18 * j;
  f4u Ea = *(const f4u*)(e1p);      f4u Eb = *(const f4u*)(e1p + 4);
  f4u Ec = *(const f4u*)(e1p + 8);  f4u Ed = *(const f4u*)(e1p + 12);
  f32x2 Ee = *(const f32x2*)(e1p + 16);
  f4u Fa = *(const f4u*)(e2p);      f4u Fb = *(const f4u*)(e2p + 4);
  f4u Fc = *(const f4u*)(e2p + 8);  f4u Fd = *(const f4u*)(e2p + 12);
  f32x2 Fe = *(const f32x2*)(e2p + 16);

  const float ax0 = A0.x, ay0 = A0.y, az0 = A0.z;
  const float ax1 = A0.w, ay1 = A1.x, az1 = A1.y;
  const float ax2 = A1.z, ay2 = A1.w, az2 = a2z;

  // ---- signed facet offsets + projections (exact ref op order) ----
  const float apb0 = ((ax0 * px + ay0 * py) + az0 * pz) - b0;
  const float apb1 = ((ax1 * px + ay1 * py) + az1 * pz) - b1;
  const float apb2 = ((ax2 * px + ay2 * py) + az2 * pz) - b2;
  const float q0x = px - apb0 * ax0, q0y = py - apb0 * ay0, q0z = pz - apb0 * az0;
  const float q1x = px - apb1 * ax1, q1y = py - apb1 * ay1, q1z = pz - apb1 * az1;
  const float q2x = px - apb2 * ax2, q2y = py - apb2 * ay2, q2z = pz - apb2 * az2;

  float* qxw = &sQ[wave][0][g][0];
  float* qyw = &sQ[wave][1][g][0];
  float* qzw = &sQ[wave][2][g][0];
  qxw[3 * j + 0] = q0x; qxw[3 * j + 1] = q1x; qxw[3 * j + 2] = q2x;
  qyw[3 * j + 0] = q0y; qyw[3 * j + 1] = q1y; qyw[3 * j + 2] = q2y;
  qzw[3 * j + 0] = q0z; qzw[3 * j + 1] = q1z; qzw[3 * j + 2] = q2z;

  // ---- is_neg per group ----
  const u64 bneg = __ballot(max3f(apb0, apb1, apb2) <= 0.0f);
  u32 negbits = 0;
  if ((bneg & 0x000000000000FFFFull) == 0x000000000000FFFFull) negbits |= 1;
  if ((bneg & 0x00000000FFFF0000ull) == 0x00000000FFFF0000ull) negbits |= 2;
  if ((bneg & 0x0000FFFF00000000ull) == 0x0000FFFF00000000ull) negbits |= 4;
  if ((bneg & 0xFFFF000000000000ull) == 0xFFFF000000000000ull) negbits |= 8;

  // ---- prebuilt broadcast pairs (loop-invariant) ----
  const f32x2 AX0 = {ax0, ax0}, AY0 = {ay0, ay0}, AZ0 = {az0, az0}, PB0 = {b0, b0};
  const f32x2 AX1 = {ax1, ax1}, AY1 = {ay1, ay1}, AZ1 = {az1, az1}, PB1 = {b1, b1};
  const f32x2 AX2 = {ax2, ax2}, AY2 = {ay2, ay2}, AZ2 = {az2, az2}, PB2 = {b2, b2};

  // ---- H^2 check: 12 iterations, 2 h-pairs (4 candidates) each ----
  u64 bad0 = 0, bad1 = 0, bad2 = 0, bad3 = 0;   // uniform, per group
  const f32x4* qx4 = (const f32x4*)qxw;
  const f32x4* qy4 = (const f32x4*)qyw;
  const f32x4* qz4 = (const f32x4*)qzw;
  #pragma unroll
  for (int it = 0; it < 12; ++it) {
    const f32x4 X = qx4[it], Y = qy4[it], Z = qz4[it];   // b128 broadcasts
    const f32x2 xlo = __builtin_shufflevector(X, X, 0, 1);
    const f32x2 xhi = __builtin_shufflevector(X, X, 2, 3);
    const f32x2 ylo = __builtin_shufflevector(Y, Y, 0, 1);
    const f32x2 yhi = __builtin_shufflevector(Y, Y, 2, 3);
    const f32x2 zlo = __builtin_shufflevector(Z, Z, 0, 1);
    const f32x2 zhi = __builtin_shufflevector(Z, Z, 2, 3);
    // lo pair: candidates h = 4it, 4it+1
    f32x2 s0 = pksub(pkadd(pkadd(pkmul(AX0, xlo), pkmul(AY0, ylo)), pkmul(AZ0, zlo)), PB0);
    f32x2 s1 = pksub(pkadd(pkadd(pkmul(AX1, xlo), pkmul(AY1, ylo)), pkmul(AZ1, zlo)), PB1);
    f32x2 s2 = pksub(pkadd(pkadd(pkmul(AX2, xlo), pkmul(AY2, ylo)), pkmul(AZ2, zlo)), PB2);
    // hi pair: candidates h = 4it+2, 4it+3
    f32x2 t0 = pksub(pkadd(pkadd(pkmul(AX0, xhi), pkmul(AY0, yhi)), pkmul(AZ0, zhi)), PB0);
    f32x2 t1 = pksub(pkadd(pkadd(pkmul(AX1, xhi), pkmul(AY1, yhi)), pkmul(AZ1, zhi)), PB1);
    f32x2 t2 = pksub(pkadd(pkadd(pkmul(AX2, xhi), pkmul(AY2, yhi)), pkmul(AZ2, zhi)), PB2);
    const u64 bl0 = __ballot(max3f(s0.x, s1.x, s2.x) <= ZEPS);
    const u64 bl1 = __ballot(max3f(s0.y, s1.y, s2.y) <= ZEPS);
    const u64 bl2 = __ballot(max3f(t0.x, t1.x, t2.x) <= ZEPS);
    const u64 bl3 = __ballot(max3f(t0.y, t1.y, t2.y) <= ZEPS);
    const int h = 4 * it;
    const u64 c0 = 1ull << h, c1 = 2ull << h, c2 = 4ull << h, c3 = 8ull << h;
    bad0 |= ((~bl0 & 0x000000000000FFFFull) ? c0 : 0) | ((~bl1 & 0x000000000000FFFFull) ? c1 : 0)
          | ((~bl2 & 0x000000000000FFFFull) ? c2 : 0) | ((~bl3 & 0x000000000000FFFFull) ? c3 : 0);
    bad1 |= ((~bl0 & 0x00000000FFFF0000ull) ? c0 : 0) | ((~bl1 & 0x00000000FFFF0000ull) ? c1 : 0)
          | ((~bl2 & 0x00000000FFFF0000ull) ? c2 : 0) | ((~bl3 & 0x00000000FFFF0000ull) ? c3 : 0);
    bad2 |= ((~bl0 & 0x0000FFFF00000000ull) ? c0 : 0) | ((~bl1 & 0x0000FFFF00000000ull) ? c1 : 0)
          | ((~bl2 & 0x0000FFFF00000000ull) ? c2 : 0) | ((~bl3 & 0x0000FFFF00000000ull) ? c3 : 0);
    bad3 |= ((~bl0 & 0xFFFF000000000000ull) ? c0 : 0) | ((~bl1 & 0xFFFF000000000000ull) ? c1 : 0)
          | ((~bl2 & 0xFFFF000000000000ull) ? c2 : 0) | ((~bl3 & 0xFFFF000000000000ull) ? c3 : 0);
  }
  const u64 MASK48 = (1ull << H) - 1;
  const bool anyface = (((~bad0) | (~bad1) | (~bad2) | (~bad3)) & MASK48) != 0;

  // ---- face path (gated; rare) ----
  float fv = INFINITY, fgx = 0.f, fgy = 0.f, fgz = 0.f;
  if (anyface) {
    const u64 badg = (g == 0) ? bad0 : (g == 1) ? bad1 : (g == 2) ? bad2 : bad3;
    const u32 mb = (u32)(badg >> (3 * j));
    float p0 = INFINITY, p1 = INFINITY, p2 = INFINITY;
    if (!(mb & 1)) {
      float dx = px - q0x, dy = py - q0y, dz = pz - q0z;
      p0 = sqrtf((dx * dx + dy * dy) + dz * dz);
    }
    if (!(mb & 2)) {
      float dx = px - q1x, dy = py - q1y, dz = pz - q1z;
      p1 = sqrtf((dx * dx + dy * dy) + dz * dz);
    }
    if (!(mb & 4)) {
      float dx = px - q2x, dy = py - q2y, dz = pz - q2z;
      p2 = sqrtf((dx * dx + dy * dy) + dz * dz);
    }
    float bv = p0; int bk = 0;
    if (p1 < bv) { bv = p1; bk = 1; }
    if (p2 < bv) { bv = p2; bk = 2; }
    u64 key = ((u64)__float_as_uint(bv) << 16) | (u32)(3 * j + bk);
    #pragma unroll
    for (int off = 8; off; off >>= 1) {
      u64 o = __shfl_xor(key, off);
      if (o < key) key = o;
    }
    fv = __uint_as_float((u32)(key >> 16));
    const int ks = (int)(key & 0xFFFF);
    const int owner = 16 * g + ks / 3;
    const int ms = ks - 3 * (ks / 3);
    const float sx0 = __shfl(ax0, owner), sx1 = __shfl(ax1, owner), sx2 = __shfl(ax2, owner);
    const float sy0 = __shfl(ay0, owner), sy1 = __shfl(ay1, owner), sy2 = __shfl(ay2, owner);
    const float sz0 = __shfl(az0, owner), sz1 = __shfl(az1, owner), sz2 = __shfl(az2, owner);
    fgx = (ms == 0) ? sx0 : (ms == 1) ? sx1 : sx2;
    fgy = (ms == 0) ? sy0 : (ms == 1) ? sy1 : sy2;
    fgz = (ms == 0) ? sz0 : (ms == 1) ? sz1 : sz2;
  }

  // ---- inside-zonotope path (gated; rare) ----
  float nv = 0.f, ngx = 0.f, ngy = 0.f, ngz = 0.f;
  if (negbits) {
    float bv = apb0; int bk = 0;                  // strict > keeps first k
    if (apb1 > bv) { bv = apb1; bk = 1; }
    if (apb2 > bv) { bv = apb2; bk = 2; }
    u32 bits = __float_as_uint(bv);
    u32 obits = (bits >> 31) ? ~bits : (bits | 0x80000000u);   // monotone
    u64 key = ((u64)obits << 16) | (u32)(0xFFFF - (3 * j + bk));
    #pragma unroll
    for (int off = 8; off; off >>= 1) {
      u64 o = __shfl_xor(key, off);
      if (o > key) key = o;
    }
    const int ks = (int)(0xFFFF - (key & 0xFFFF));
    const int owner = 16 * g + ks / 3;
    const int ms = ks - 3 * (ks / 3);
    const float v0 = __shfl(apb0, owner), v1 = __shfl(apb1, owner), v2 = __shfl(apb2, owner);
    nv = (ms == 0) ? v0 : (ms == 1) ? v1 : v2;
    const float sx0 = __shfl(ax0, owner), sx1 = __shfl(ax1, owner), sx2 = __shfl(ax2, owner);
    const float sy0 = __shfl(ay0, owner), sy1 = __shfl(ay1, owner), sy2 = __shfl(ay2, owner);
    const float sz0 = __shfl(az0, owner), sz1 = __shfl(az1, owner), sz2 = __shfl(az2, owner);
    ngx = (ms == 0) ? sx0 : (ms == 1) ? sx1 : sx2;
    ngy = (ms == 0) ? sy0 : (ms == 1) ? sy1 : sy2;
    ngz = (ms == 0) ? sz0 : (ms == 1) ? sz1 : sz2;
  }

  // ---- edge distances: 3 packed pairs (edges 2t,2t+1), exact ref math ----
  float bed = INFINITY, bvx = 0.f, bvy = 0.f, bvz = 0.f;
  {
    const f32x2 Px = {px, px}, Py = {py, py}, Pz = {pz, pz};
    #pragma unroll
    for (int t = 0; t < 3; ++t) {
      f32x2 X1, Y1, Z1, X2, Y2, Z2;
      if (t == 0) {
        X1 = f32x2{Ea.x, Ea.w}; Y1 = f32x2{Ea.y, Eb.x}; Z1 = f32x2{Ea.z, Eb.y};
        X2 = f32x2{Fa.x, Fa.w}; Y2 = f32x2{Fa.y, Fb.x}; Z2 = f32x2{Fa.z, Fb.y};
      } else if (t == 1) {
        X1 = f32x2{Eb.z, Ec.y}; Y1 = f32x2{Eb.w, Ec.z}; Z1 = f32x2{Ec.x, Ec.w};
        X2 = f32x2{Fb.z, Fc.y}; Y2 = f32x2{Fb.w, Fc.z}; Z2 = f32x2{Fc.x, Fc.w};
      } else {
        X1 = f32x2{Ed.x, Ed.w}; Y1 = f32x2{Ed.y, Ee.x}; Z1 = f32x2{Ed.z, Ee.y};
        X2 = f32x2{Fd.x, Fd.w}; Y2 = f32x2{Fd.y, Fe.x}; Z2 = f32x2{Fd.z, Fe.y};
      }
      const f32x2 dx = pksub(X2, X1), dy = pksub(Y2, Y1), dz = pksub(Z2, Z1);
      const f32x2 den = pkadd(pkadd(pkmul(dx, dx), pkmul(dy, dy)), pkmul(dz, dz));
      const f32x2 wx = pksub(Px, X1), wy = pksub(Py, Y1), wz = pksub(Pz, Z1);
      const f32x2 num = pkadd(pkadd(pkmul(wx, dx), pkmul(wy, dy)), pkmul(wz, dz));
      const float th0 = num.x / den.x;             // exact IEEE divs (ref)
      const float th1 = num.y / den.y;
      const float t0 = th0 < 0.0f ? 0.0f : (th0 > 1.0f ? 1.0f : th0);
      const float t1 = th1 < 0.0f ? 0.0f : (th1 > 1.0f ? 1.0f : th1);
      const f32x2 tv = {t0, t1};
      const f32x2 Vx = pkadd(X1, pkmul(tv, dx));   // ref: v1 + t*d
      const f32x2 Vy = pkadd(Y1, pkmul(tv, dy));
      const f32x2 Vz = pkadd(Z1, pkmul(tv, dz));
      const f32x2 Ex = pksub(Px, Vx), Ey = pksub(Py, Vy), Ez = pksub(Pz, Vz);
      const f32x2 ss = pkadd(pkadd(pkmul(Ex, Ex), pkmul(Ey, Ey)), pkmul(Ez, Ez));
      const float ed0 = sqrtf(ss.x);
      const float ed1 = sqrtf(ss.y);
      const bool pick = ed1 < ed0;                 // tie -> lower index
      const float edp = pick ? ed1 : ed0;
      if (edp < bed) {                             // strict -> first index
        bed = edp;
        bvx = pick ? Vx.y : Vx.x;
        bvy = pick ? Vy.y : Vy.x;
        bvz = pick ? Vz.y : Vz.x;
      }
    }
  }
  // ---- edge reduction: f32 value-min butterfly + ballot/ctz winner ----
  float m = bed;
  #pragma unroll
  for (int off = 8; off; off >>= 1) {
    const float o = __shfl_xor(m, off);
    m = fminf(m, o);
  }
  const u64 cand = __ballot(bed == m);             // per-group fields
  const u32 gf = (u32)((cand >> (16 * g)) & 0xFFFFu);
  const int wl = 16 * g + __builtin_ctz(gf);       // first winner (index order)
  const float wvx = __shfl(bvx, wl);
  const float wvy = __shfl(bvy, wl);
  const float wvz = __shfl(bvz, wl);

  // ---- combine; lanes j=0..2 write grad comps, j=3 writes dist ----
  const bool isneg = (negbits >> g) & 1;
  const bool use_edge = (m < fv);
  const float pd = (j == 0) ? px : (j == 1) ? py : pz;
  const float wd = (j == 0) ? wvx : (j == 1) ? wvy : wvz;
  const float fd = (j == 0) ? fgx : (j == 1) ? fgy : fgz;
  const float nd = (j == 0) ? ngx : (j == 1) ? ngy : ngz;
  float dist, gnum, gden = 1.0f;
  if (isneg) {
    dist = nv; gnum = nd;
  } else if (use_edge) {
    dist = m; gnum = pd - wd; gden = m;
  } else {
    dist = fv; gnum = fd;
  }
  const float gr = gnum / gden;
  if (j < 3) out[(size_t)N + 3 * (size_t)n + j] = gr;
  if (j == 3) out[n] = dist;
}

extern "C" void kernel_launch(void* const* d_in, const int* in_sizes, int n_in,
                              void* d_out, int out_size, void* d_ws, size_t ws_size,
                              hipStream_t stream) {
  const float* point = (const float*)d_in[0];
  const float* Ag    = (const float*)d_in[1];
  const float* bg    = (const float*)d_in[2];
  const float* v1g   = (const float*)d_in[3];
  const float* v2g   = (const float*)d_in[4];
  float* out = (float*)d_out;

  const int N = in_sizes[0] / 3;
  const int ppb = WPB * PPW;   // 16 points per block
  const int blocks = (N + ppb - 1) / ppb;
  zono_dist_kernel<<<blocks, WPB * 64, 0, stream>>>(point, Ag, bg, v1g, v2g, out, N);
}